// Round 5
// baseline (551.617 us; speedup 1.0000x reference)
//
#include <hip/hip_runtime.h>
#include <hip/hip_bf16.h>

// HybridBridge round 5: all-async mix1 K-loop (x*ao precomputed into pbuf),
// stats+attn fused, concat-LN folded into final, prep kernels fused.
// B=8, L=4096, D=512, C=256, T=2, H=2, HD=256. N = 32768 rows.

#define N_TOK 32768

typedef unsigned short u16;
typedef __attribute__((ext_vector_type(8))) __bf16 bf16x8;
typedef __attribute__((ext_vector_type(4))) float f32x4;

__device__ __forceinline__ float bf2f(unsigned int h) { return __uint_as_float(h << 16); }
__device__ __forceinline__ u16 f2bf(float f) {
    unsigned int u = __float_as_uint(f);
    u += 0x7FFFu + ((u >> 16) & 1u);   // RNE
    return (u16)(u >> 16);
}
__device__ __forceinline__ void load8(const u16* p, float* v) {
    uint4 u = *(const uint4*)p;
    v[0] = bf2f(u.x & 0xffffu); v[1] = bf2f(u.x >> 16);
    v[2] = bf2f(u.y & 0xffffu); v[3] = bf2f(u.y >> 16);
    v[4] = bf2f(u.z & 0xffffu); v[5] = bf2f(u.z >> 16);
    v[6] = bf2f(u.w & 0xffffu); v[7] = bf2f(u.w >> 16);
}
__device__ __forceinline__ uint4 pack8(const float* v) {
    uint4 u;
    u.x = (unsigned)f2bf(v[0]) | ((unsigned)f2bf(v[1]) << 16);
    u.y = (unsigned)f2bf(v[2]) | ((unsigned)f2bf(v[3]) << 16);
    u.z = (unsigned)f2bf(v[4]) | ((unsigned)f2bf(v[5]) << 16);
    u.w = (unsigned)f2bf(v[6]) | ((unsigned)f2bf(v[7]) << 16);
    return u;
}
__device__ __forceinline__ void async16(const u16* g, u16* lds) {
    __builtin_amdgcn_global_load_lds(
        (const __attribute__((address_space(1))) unsigned int*)g,
        (__attribute__((address_space(3))) unsigned int*)lds, 16, 0, 0);
}

// ==== prep: foldq | wconv(concat_w) | wconv(mix_w2) | wmix1 | ctxbf ======
__global__ void prep_kernel(const float* __restrict__ in_proj_w,
                            const float* __restrict__ in_proj_b,
                            const float* __restrict__ qb,
                            const float* __restrict__ concat_w,
                            const float* __restrict__ mix_w1,
                            const float* __restrict__ mix_w2,
                            const float* __restrict__ context,
                            float* __restrict__ bqp,
                            u16* __restrict__ cwbf, u16* __restrict__ m1bf,
                            u16* __restrict__ m2bf, u16* __restrict__ ctxbf) {
    const int bid = blockIdx.x;
    const int tid = threadIdx.x;
    if (bid < 128) {
        // foldq: bqp[j] = bq[j] + Wq[j,:] . q_ln_b
        const int wave = tid >> 6, lane = tid & 63;
        const int j = bid * 4 + wave;
        const int i = lane * 8;
        float4 w0 = *(const float4*)(in_proj_w + (size_t)j * 512 + i);
        float4 w1 = *(const float4*)(in_proj_w + (size_t)j * 512 + i + 4);
        float4 b0 = *(const float4*)(qb + i);
        float4 b1 = *(const float4*)(qb + i + 4);
        float p1 = w0.x*b0.x + w0.y*b0.y + w0.z*b0.z + w0.w*b0.w
                 + w1.x*b1.x + w1.y*b1.y + w1.z*b1.z + w1.w*b1.w;
        for (int m = 1; m < 64; m <<= 1) p1 += __shfl_xor(p1, m, 64);
        if (lane == 0) bqp[j] = in_proj_b[j] + p1;
    } else if (bid < 320) {
        int i = (bid - 128) * 256 + tid;           // < 49152
        const float* s = concat_w + (size_t)i * 8;
        float4 a = *(const float4*)s;
        float4 b = *(const float4*)(s + 4);
        float v[8] = {a.x, a.y, a.z, a.w, b.x, b.y, b.z, b.w};
        *(uint4*)(cwbf + (size_t)i * 8) = pack8(v);
    } else if (bid < 576) {
        int i = (bid - 320) * 256 + tid;           // < 65536
        const float* s = mix_w2 + (size_t)i * 8;
        float4 a = *(const float4*)s;
        float4 b = *(const float4*)(s + 4);
        float v[8] = {a.x, a.y, a.z, a.w, b.x, b.y, b.z, b.w};
        *(uint4*)(m2bf + (size_t)i * 8) = pack8(v);
    } else if (bid < 1344) {
        int idx = (bid - 576) * 256 + tid;         // < 196608
        int n = idx / 192;
        int k = (idx - n * 192) * 8;
        const float* base = mix_w1 + (size_t)n * 2048;
        float v[8];
        if (k < 512) {
            #pragma unroll
            for (int e = 0; e < 8; e++) v[e] = base[k + e] + base[1024 + k + e];
        } else if (k < 1024) {
            #pragma unroll
            for (int e = 0; e < 8; e++) v[e] = base[k + e] - base[512 + k + e];
        } else {
            #pragma unroll
            for (int e = 0; e < 8; e++) v[e] = base[512 + k + e];
        }
        *(uint4*)(m1bf + (size_t)n * 1536 + k) = pack8(v);
    } else {
        for (int i = tid; i < 2048; i += 256)
            ctxbf[i] = f2bf(context[i]);
    }
}

// ==== context stage A: film gamma/beta, gate, gelu(h). wave-per-output ===
__global__ void ctx_stage_a(const float* __restrict__ context,
                            const float* __restrict__ film_w, const float* __restrict__ film_b,
                            const float* __restrict__ gate_w, const float* __restrict__ gate_b,
                            const float* __restrict__ ctx_w1, const float* __restrict__ ctx_b1,
                            float* __restrict__ gb1, float* __restrict__ betab,
                            float* __restrict__ gateb, float* __restrict__ hbuf) {
    const int wave = threadIdx.x >> 6, lane = threadIdx.x & 63;
    const int widx = blockIdx.x * 4 + wave;       // 0..16383
    const int b   = widx >> 11;
    const int j2  = widx & 2047;
    const int cat = j2 >> 9;
    const int j   = j2 & 511;
    const float* wrow;
    if      (cat == 0) wrow = film_w + (size_t)j * 256;
    else if (cat == 1) wrow = film_w + (size_t)(512 + j) * 256;
    else if (cat == 2) wrow = gate_w + (size_t)j * 256;
    else               wrow = ctx_w1 + (size_t)j * 256;
    float4 wv = *(const float4*)(wrow + lane * 4);
    float4 cv = *(const float4*)(context + b * 256 + lane * 4);
    float s = wv.x * cv.x + wv.y * cv.y + wv.z * cv.z + wv.w * cv.w;
    for (int m = 1; m < 64; m <<= 1) s += __shfl_xor(s, m, 64);
    if (lane == 0) {
        if      (cat == 0) gb1[b * 512 + j]   = 1.0f + s + film_b[j];
        else if (cat == 1) betab[b * 512 + j] = s + film_b[512 + j];
        else if (cat == 2) gateb[b * 512 + j] = 1.f / (1.f + expf(-(s + gate_b[j])));
        else {
            float hv = s + ctx_b1[j];
            hbuf[b * 512 + j] = 0.5f * hv * (1.0f + erff(hv * 0.70710678118654752f));
        }
    }
}

// ==== context stage B: ctx_tok = h @ ctx_w2^T + b2 =======================
__global__ void ctx_stage_b(const float* __restrict__ hbuf,
                            const float* __restrict__ ctx_w2, const float* __restrict__ ctx_b2,
                            float* __restrict__ tokbuf) {
    const int wave = threadIdx.x >> 6, lane = threadIdx.x & 63;
    const int widx = blockIdx.x * 4 + wave;       // 0..8191
    const int b = widx >> 10;
    const int j = widx & 1023;
    const float* wrow = ctx_w2 + (size_t)j * 512 + lane * 8;
    const float* hr   = hbuf + b * 512 + lane * 8;
    float4 w0 = *(const float4*)wrow, w1 = *(const float4*)(wrow + 4);
    float4 h0 = *(const float4*)hr,   h1 = *(const float4*)(hr + 4);
    float s = w0.x*h0.x + w0.y*h0.y + w0.z*h0.z + w0.w*h0.w
            + w1.x*h1.x + w1.y*h1.y + w1.z*h1.z + w1.w*h1.w;
    for (int m = 1; m < 64; m <<= 1) s += __shfl_xor(s, m, 64);
    if (lane == 0) tokbuf[b * 1024 + j] = s + ctx_b2[j];
}

// ==== context stage C: k,v = tok @ wk/wv^T + b ===========================
__global__ void ctx_stage_c(const float* __restrict__ tokbuf,
                            const float* __restrict__ in_proj_w, const float* __restrict__ in_proj_b,
                            float* __restrict__ kbuf, float* __restrict__ vbuf) {
    const int wave = threadIdx.x >> 6, lane = threadIdx.x & 63;
    const int widx = blockIdx.x * 4 + wave;       // 0..16383
    const int b  = widx >> 11;
    const int r  = widx & 2047;
    const int t  = r >> 10;
    const int kv = (r >> 9) & 1;
    const int j  = r & 511;
    const float* wrow = in_proj_w + (size_t)(512 + kv * 512 + j) * 512 + lane * 8;
    const float* tk   = tokbuf + (b * 2 + t) * 512 + lane * 8;
    float4 w0 = *(const float4*)wrow, w1 = *(const float4*)(wrow + 4);
    float4 t0 = *(const float4*)tk,   t1 = *(const float4*)(tk + 4);
    float s = w0.x*t0.x + w0.y*t0.y + w0.z*t0.z + w0.w*t0.w
            + w1.x*t1.x + w1.y*t1.y + w1.z*t1.z + w1.w*t1.w;
    for (int m = 1; m < 64; m <<= 1) s += __shfl_xor(s, m, 64);
    if (lane == 0) {
        float v = s + in_proj_b[512 + kv * 512 + j];
        if (kv == 0) kbuf[(b * 2 + t) * 512 + j] = v;
        else         vbuf[(b * 2 + t) * 512 + j] = v;
    }
}

// ==== context stage D: u/su/c0 (bid<32) and vo (bid>=32) =================
__global__ void ctx_stage_d(const float* __restrict__ in_proj_w,
                            const float* __restrict__ out_proj_w,
                            const float* __restrict__ qg, const float* __restrict__ bqp,
                            const float* __restrict__ kbuf, const float* __restrict__ vbuf,
                            float* __restrict__ ubuf, float* __restrict__ vobuf,
                            float* __restrict__ subuf, float* __restrict__ c0buf) {
    const int tid = threadIdx.x;
    __shared__ float sh[256];
    __shared__ float red[256];
    if (blockIdx.x < 32) {
        const int bid = blockIdx.x;
        const int b = bid >> 2, idx = bid & 3;
        const int t = idx >> 1, h = idx & 1;
        sh[tid] = kbuf[(b * 2 + t) * 512 + h * 256 + tid];
        __syncthreads();
        float a0 = 0.f, a1 = 0.f;
        #pragma unroll 4
        for (int dd = 0; dd < 256; dd++) {
            const float kv = sh[dd];
            const float* wr = in_proj_w + (size_t)(h * 256 + dd) * 512;
            a0 += kv * wr[tid];
            a1 += kv * wr[tid + 256];
        }
        float u0 = a0 * qg[tid], u1 = a1 * qg[tid + 256];
        ubuf[bid * 512 + tid]       = u0;
        ubuf[bid * 512 + tid + 256] = u1;
        red[tid] = u0 + u1;
        __syncthreads();
        for (int s = 128; s > 0; s >>= 1) { if (tid < s) red[tid] += red[tid + s]; __syncthreads(); }
        if (tid == 0) subuf[bid] = red[0];
        __syncthreads();
        red[tid] = bqp[h * 256 + tid] * sh[tid];
        __syncthreads();
        for (int s = 128; s > 0; s >>= 1) { if (tid < s) red[tid] += red[tid + s]; __syncthreads(); }
        if (tid == 0) c0buf[bid] = red[0];
    } else {
        const int bid = blockIdx.x - 32;
        const int b = bid >> 2, idx = bid & 3;
        const int t = idx >> 1, h = idx & 1;
        sh[tid] = vbuf[(b * 2 + t) * 512 + h * 256 + tid];
        __syncthreads();
        const float* w0 = out_proj_w + (size_t)tid * 512 + h * 256;
        const float* w1 = out_proj_w + (size_t)(tid + 256) * 512 + h * 256;
        float acc0 = 0.f, acc1 = 0.f;
        #pragma unroll 2
        for (int dd = 0; dd < 256; dd += 4) {
            float4 x0 = *(const float4*)(w0 + dd);
            float4 x1 = *(const float4*)(w1 + dd);
            acc0 += x0.x*sh[dd] + x0.y*sh[dd+1] + x0.z*sh[dd+2] + x0.w*sh[dd+3];
            acc1 += x1.x*sh[dd] + x1.y*sh[dd+1] + x1.z*sh[dd+2] + x1.w*sh[dd+3];
        }
        vobuf[bid * 512 + tid]       = acc0;
        vobuf[bid * 512 + tid + 256] = acc1;
    }
}

// ==== fused stats + attn: per-row mean/rstd, xbf, ao, x*ao ===============
__global__ void statsattn_kernel(const float* __restrict__ x, float* __restrict__ stats,
                                 u16* __restrict__ mixA, u16* __restrict__ pbuf,
                                 const float* __restrict__ ubuf, const float* __restrict__ subuf,
                                 const float* __restrict__ c0buf, const float* __restrict__ vobuf,
                                 const float* __restrict__ ob) {
    const int wave = threadIdx.x >> 6, lane = threadIdx.x & 63;
    const size_t row = (size_t)blockIdx.x * 4 + wave;
    const int b = (int)(row >> 12);
    const float* xr = x + row * 512 + lane * 8;
    float4 a = *(const float4*)xr;
    float4 c = *(const float4*)(xr + 4);
    float v[8] = {a.x, a.y, a.z, a.w, c.x, c.y, c.z, c.w};
    float s = 0.f, ss = 0.f;
    #pragma unroll
    for (int e = 0; e < 8; e++) { s += v[e]; ss += v[e] * v[e]; }
    // 4 attention score partial dots
    float sd[4];
    #pragma unroll
    for (int idx = 0; idx < 4; idx++) {
        const float* u = ubuf + (b * 4 + idx) * 512 + lane * 8;
        float4 u0 = *(const float4*)u, u1 = *(const float4*)(u + 4);
        sd[idx] = v[0]*u0.x + v[1]*u0.y + v[2]*u0.z + v[3]*u0.w
                + v[4]*u1.x + v[5]*u1.y + v[6]*u1.z + v[7]*u1.w;
    }
    for (int m = 1; m < 64; m <<= 1) {
        s += __shfl_xor(s, m, 64); ss += __shfl_xor(ss, m, 64);
        #pragma unroll
        for (int idx = 0; idx < 4; idx++) sd[idx] += __shfl_xor(sd[idx], m, 64);
    }
    const float mean = s * (1.f / 512.f);
    const float rstd = rsqrtf(ss * (1.f / 512.f) - mean * mean + 1e-5f);
    *(uint4*)(mixA + row * 1024 + lane * 8) = pack8(v);
    if (lane == 0) { stats[row * 2] = mean; stats[row * 2 + 1] = rstd; }
    float sc[4];
    #pragma unroll
    for (int idx = 0; idx < 4; idx++)
        sc[idx] = (rstd * (sd[idx] - mean * subuf[b * 4 + idx]) + c0buf[b * 4 + idx]) * (1.f / 16.f);
    float p[4];
    #pragma unroll
    for (int h = 0; h < 2; h++) {
        float s0 = sc[h], s1 = sc[2 + h];          // t=0, t=1
        float mx = fmaxf(s0, s1);
        float e0 = expf(s0 - mx), e1 = expf(s1 - mx);
        float inv = 1.f / (e0 + e1);
        p[h] = e0 * inv; p[2 + h] = e1 * inv;
    }
    const float* vo0 = vobuf + (b * 4 + 0) * 512 + lane * 8;
    const float* vo1 = vobuf + (b * 4 + 1) * 512 + lane * 8;
    const float* vo2 = vobuf + (b * 4 + 2) * 512 + lane * 8;
    const float* vo3 = vobuf + (b * 4 + 3) * 512 + lane * 8;
    const float* obp = ob + lane * 8;
    float o[8], pr[8];
    #pragma unroll
    for (int e = 0; e < 8; e++) {
        o[e] = p[0]*vo0[e] + p[1]*vo1[e] + p[2]*vo2[e] + p[3]*vo3[e] + obp[e];
        pr[e] = v[e] * o[e];
    }
    *(uint4*)(mixA + row * 1024 + 512 + lane * 8) = pack8(o);
    *(uint4*)(pbuf + row * 512 + lane * 8) = pack8(pr);
}

// ==== MFMA GEMM, XOR-swizzled LDS, vectorized LDS-transpose epilogue =====
// AMODE 0: A = A0 (bf16, leading dim lda)
// AMODE 1: A = [A0(xbf, ld 1024) | A1(ctxbf, per-batch broadcast)], K=768
// AMODE 2: A = [A0(mixA, ld 1024, k<1024) | A1(pbuf, ld 512)], K=1536, all async
template<int AMODE, bool RELU>
__launch_bounds__(256)
__global__ void mfma_gemm(const u16* __restrict__ A0, const u16* __restrict__ A1,
                          const u16* __restrict__ Wb, const float* __restrict__ bias,
                          u16* __restrict__ out, const int K, const int lda, const int ldo) {
    __shared__ __align__(16) u16 S[16384];
    u16* As = S;
    u16* Bs = S + 8192;
    const int tid = threadIdx.x;
    const int w = tid >> 6, l = tid & 63;
    const int wm = w >> 1, wn = w & 1;
    const size_t m0 = (size_t)blockIdx.x * 128;
    const int n0 = blockIdx.y * 128;
    const int rb = w * 8 + (l >> 3);              // staging row base 0..31
    const int kswz = ((l & 7) ^ (l >> 3)) * 8;    // XOR-swizzled k offset
    const int bidx = (int)(m0 >> 12);
    const int quad = l >> 4, lc = l & 15;

    f32x4 acc[4][4];
    #pragma unroll
    for (int i = 0; i < 4; i++)
        #pragma unroll
        for (int j = 0; j < 4; j++) acc[i][j] = (f32x4){0.f, 0.f, 0.f, 0.f};

    for (int k0 = 0; k0 < K; k0 += 64) {
        __syncthreads();
        // ---- stage A tile 128x64 (swizzled chunks, all async) ----
        if constexpr (AMODE == 0) {
            #pragma unroll
            for (int r = 0; r < 4; r++)
                async16(A0 + (m0 + r * 32 + rb) * (size_t)lda + k0 + kswz, &As[r * 2048 + w * 512]);
        } else if constexpr (AMODE == 1) {
            if (k0 < 512) {
                #pragma unroll
                for (int r = 0; r < 4; r++)
                    async16(A0 + (m0 + r * 32 + rb) * (size_t)lda + k0 + kswz, &As[r * 2048 + w * 512]);
            } else {
                #pragma unroll
                for (int r = 0; r < 4; r++)
                    async16(A1 + bidx * 256 + (k0 - 512) + kswz, &As[r * 2048 + w * 512]);
            }
        } else {
            if (k0 < 1024) {       // [x | ao] in mixA (ld 1024)
                #pragma unroll
                for (int r = 0; r < 4; r++)
                    async16(A0 + (m0 + r * 32 + rb) * (size_t)1024 + k0 + kswz, &As[r * 2048 + w * 512]);
            } else {               // x*ao in pbuf (ld 512)
                #pragma unroll
                for (int r = 0; r < 4; r++)
                    async16(A1 + (m0 + r * 32 + rb) * (size_t)512 + (k0 - 1024) + kswz, &As[r * 2048 + w * 512]);
            }
        }
        // ---- stage B tile 128x64 ----
        #pragma unroll
        for (int r = 0; r < 4; r++)
            async16(Wb + (size_t)(n0 + r * 32 + rb) * K + k0 + kswz, &Bs[r * 2048 + w * 512]);
        __syncthreads();
        // ---- compute ----
        #pragma unroll
        for (int kk = 0; kk < 2; kk++) {
            bf16x8 af[4], bff[4];
            #pragma unroll
            for (int t = 0; t < 4; t++) {
                const int ch = ((kk << 2) | quad) ^ (lc & 7);
                af[t]  = *(const bf16x8*)&As[(wm * 64 + t * 16 + lc) * 64 + ch * 8];
                bff[t] = *(const bf16x8*)&Bs[(wn * 64 + t * 16 + lc) * 64 + ch * 8];
            }
            #pragma unroll
            for (int i = 0; i < 4; i++)
                #pragma unroll
                for (int j = 0; j < 4; j++)
                    acc[i][j] = __builtin_amdgcn_mfma_f32_16x16x32_bf16(af[i], bff[j], acc[i][j], 0, 0, 0);
        }
    }

    // ---- epilogue: bias/relu -> LDS (64x136 pad) -> coalesced b128 stores
    float bv[4];
    #pragma unroll
    for (int j = 0; j < 4; j++) bv[j] = bias[n0 + wn * 64 + j * 16 + lc];
    const int erow = tid >> 2;           // 0..63
    const int ecb  = (tid & 3) * 32;
    __syncthreads();
    #pragma unroll
    for (int p = 0; p < 2; p++) {
        if (p) __syncthreads();
        if (wm == p) {
            #pragma unroll
            for (int i = 0; i < 4; i++)
                #pragma unroll
                for (int j = 0; j < 4; j++)
                    #pragma unroll
                    for (int reg = 0; reg < 4; reg++) {
                        float vv = acc[i][j][reg] + bv[j];
                        if (RELU) vv = fmaxf(vv, 0.f);
                        S[(i * 16 + quad * 4 + reg) * 136 + wn * 64 + j * 16 + lc] = f2bf(vv);
                    }
        }
        __syncthreads();
        #pragma unroll
        for (int q = 0; q < 4; q++)
            *(uint4*)(out + (m0 + p * 64 + erow) * (size_t)ldo + n0 + ecb + q * 8)
                = *(const uint4*)&S[erow * 136 + ecb + q * 8];
    }
}

// ==== final: upd_c = LN(bufc); LN(base + gate*mask*(upd_c+upd_a)) ========
__global__ void final_kernel(const u16* __restrict__ mixA, const float* __restrict__ stats,
                             const u16* __restrict__ bufc,
                             const float* __restrict__ cg, const float* __restrict__ cb,
                             const float* __restrict__ gb1, const float* __restrict__ betab,
                             const float* __restrict__ gateb, const int* __restrict__ mask,
                             const float* __restrict__ fg, const float* __restrict__ fb,
                             const float* __restrict__ og, const float* __restrict__ ob,
                             float* __restrict__ out) {
    const int wave = threadIdx.x >> 6, lane = threadIdx.x & 63;
    const size_t row = (size_t)blockIdx.x * 4 + wave;
    const int b = (int)(row >> 12);
    const int c0 = lane * 8;
    float xv[8], uc[8], ua[8];
    load8(mixA + row * 1024 + c0, xv);          // xbf
    load8(mixA + row * 1024 + 512 + c0, ua);    // upd_a
    load8(bufc + row * 512 + c0, uc);           // relu'd concat out (pre-LN)
    // concat LN (row-local)
    float sc = 0.f, ssc = 0.f;
    #pragma unroll
    for (int e = 0; e < 8; e++) { sc += uc[e]; ssc += uc[e] * uc[e]; }
    for (int m = 1; m < 64; m <<= 1) { sc += __shfl_xor(sc, m, 64); ssc += __shfl_xor(ssc, m, 64); }
    const float mc = sc * (1.f / 512.f);
    const float rc = rsqrtf(ssc * (1.f / 512.f) - mc * mc + 1e-5f);
    const float mean = stats[row * 2], rstd = stats[row * 2 + 1];
    const float mf = (mask[row] != 0) ? 1.f : 0.f;
    float y[8];
    float s = 0.f, ss = 0.f;
    #pragma unroll
    for (int e = 0; e < 8; e++) {
        int c = c0 + e;
        float ucn = (uc[e] - mc) * rc * cg[c] + cb[c];
        float xh = (xv[e] - mean) * rstd;
        float base = gb1[b * 512 + c] * (xh * fg[c] + fb[c]) + betab[b * 512 + c];
        float yv = base + gateb[b * 512 + c] * mf * (ucn + ua[e]);
        y[e] = yv; s += yv; ss += yv * yv;
    }
    for (int m = 1; m < 64; m <<= 1) { s += __shfl_xor(s, m, 64); ss += __shfl_xor(ss, m, 64); }
    float mean2 = s * (1.f / 512.f);
    float rstd2 = rsqrtf(ss * (1.f / 512.f) - mean2 * mean2 + 1e-5f);
    float o[8];
    #pragma unroll
    for (int e = 0; e < 8; e++) {
        int c = c0 + e;
        o[e] = (y[e] - mean2) * rstd2 * og[c] + ob[c];
    }
    *(float4*)(out + row * 512 + c0)     = make_float4(o[0], o[1], o[2], o[3]);
    *(float4*)(out + row * 512 + c0 + 4) = make_float4(o[4], o[5], o[6], o[7]);
}

extern "C" void kernel_launch(void* const* d_in, const int* in_sizes, int n_in,
                              void* d_out, int out_size, void* d_ws, size_t ws_size,
                              hipStream_t stream) {
    const float* x          = (const float*)d_in[0];
    const float* context    = (const float*)d_in[1];
    const int*   mask       = (const int*)d_in[2];
    const float* film_ln_g  = (const float*)d_in[3];
    const float* film_ln_b  = (const float*)d_in[4];
    const float* film_w     = (const float*)d_in[5];
    const float* film_b     = (const float*)d_in[6];
    const float* concat_w   = (const float*)d_in[7];
    const float* concat_b   = (const float*)d_in[8];
    const float* concat_ln_g= (const float*)d_in[9];
    const float* concat_ln_b= (const float*)d_in[10];
    const float* ctx_w1     = (const float*)d_in[11];
    const float* ctx_b1     = (const float*)d_in[12];
    const float* ctx_w2     = (const float*)d_in[13];
    const float* ctx_b2     = (const float*)d_in[14];
    const float* q_ln_g     = (const float*)d_in[15];
    const float* q_ln_b     = (const float*)d_in[16];
    const float* in_proj_w  = (const float*)d_in[17];
    const float* in_proj_b  = (const float*)d_in[18];
    const float* out_proj_w = (const float*)d_in[19];
    const float* out_proj_b = (const float*)d_in[20];
    const float* mix_w1     = (const float*)d_in[21];
    const float* mix_b1     = (const float*)d_in[22];
    const float* mix_w2     = (const float*)d_in[23];
    const float* mix_b2     = (const float*)d_in[24];
    const float* out_ln_g   = (const float*)d_in[25];
    const float* out_ln_b   = (const float*)d_in[26];
    const float* gate_w     = (const float*)d_in[27];
    const float* gate_b     = (const float*)d_in[28];
    float* out = (float*)d_out;

    // ---- workspace layout (~156.5 MB) ----
    float* gb1    = (float*)d_ws;            // 4096
    float* betab  = gb1 + 4096;
    float* gateb  = betab + 4096;
    float* kbuf   = gateb + 4096;            // 8192
    float* vbuf   = kbuf + 8192;
    float* bqp    = vbuf + 8192;             // 512
    float* hbuf   = bqp + 512;               // 4096
    float* tokbuf = hbuf + 4096;             // 8192
    float* ubuf   = tokbuf + 8192;           // 16384
    float* vobuf  = ubuf + 16384;            // 16384
    float* subuf  = vobuf + 16384;           // 32
    float* c0buf  = subuf + 32;              // 32
    float* stats  = c0buf + 32;              // 65536
    u16* ctxbf = (u16*)(stats + 65536);      // 2048
    u16* cwbf  = ctxbf + 2048;               // 393216
    u16* m1bf  = cwbf + 393216;              // 1572864
    u16* m2bf  = m1bf + 1572864;             // 524288
    u16* mixA  = m2bf + 524288;                 // 32768*1024 [xbf | ao->upd_a]
    u16* bufc  = mixA + (size_t)N_TOK * 1024;   // 32768*512  relu concat out
    u16* pbuf  = bufc + (size_t)N_TOK * 512;    // 32768*512  x*ao
    u16* bufh  = pbuf + (size_t)N_TOK * 512;    // 8192*1024  (quarter, reused)

    prep_kernel<<<1345, 256, 0, stream>>>(in_proj_w, in_proj_b, q_ln_b,
                                          concat_w, mix_w1, mix_w2, context,
                                          bqp, cwbf, m1bf, m2bf, ctxbf);
    ctx_stage_a<<<4096, 256, 0, stream>>>(context, film_w, film_b, gate_w, gate_b,
                                          ctx_w1, ctx_b1, gb1, betab, gateb, hbuf);
    ctx_stage_b<<<2048, 256, 0, stream>>>(hbuf, ctx_w2, ctx_b2, tokbuf);
    ctx_stage_c<<<4096, 256, 0, stream>>>(tokbuf, in_proj_w, in_proj_b, kbuf, vbuf);
    ctx_stage_d<<<64, 256, 0, stream>>>(in_proj_w, out_proj_w, q_ln_g, bqp,
                                        kbuf, vbuf, ubuf, vobuf, subuf, c0buf);

    statsattn_kernel<<<N_TOK / 4, 256, 0, stream>>>(x, stats, mixA, pbuf,
                                                    ubuf, subuf, c0buf, vobuf, out_proj_b);

    // concat: relu([x|ctx] @ concat_w^T + b) -> bufc (LN deferred to final)
    mfma_gemm<1, true><<<dim3(256, 4), 256, 0, stream>>>(
        mixA, ctxbf, cwbf, concat_b, bufc, 768, 1024, 512);

    // mix MLP in four row-chunks of 8192 (bufh quarter-sized, reused)
    for (int c = 0; c < 4; c++) {
        const size_t rowbase = (size_t)c * 8192;
        mfma_gemm<2, true><<<dim3(64, 8), 256, 0, stream>>>(
            mixA + rowbase * 1024, pbuf + rowbase * 512, m1bf, mix_b1,
            bufh, 1536, 1024, 1024);
        mfma_gemm<0, false><<<dim3(64, 4), 256, 0, stream>>>(
            bufh, nullptr, m2bf, mix_b2,
            mixA + rowbase * 1024 + 512, 1024, 1024, 1024);
    }

    final_kernel<<<N_TOK / 4, 256, 0, stream>>>(mixA, stats, bufc,
                                                concat_ln_g, concat_ln_b,
                                                gb1, betab, gateb, mask,
                                                film_ln_g, film_ln_b,
                                                out_ln_g, out_ln_b, out);
    (void)in_sizes; (void)n_in; (void)out_size; (void)ws_size;
}

// Round 6
// 506.637 us; speedup vs baseline: 1.0888x; 1.0888x over previous
//
#include <hip/hip_runtime.h>
#include <hip/hip_bf16.h>

// HybridBridge round 6: half-interleaved mix pipeline (pbufH reused across
// halves), all GEMM dispatches >= 512 blocks, statsattn 2-rows-per-wave ILP.
// B=8, L=4096, D=512, C=256, T=2, H=2, HD=256. N = 32768 rows.

#define N_TOK 32768
#define HALF_ROWS 16384

typedef unsigned short u16;
typedef __attribute__((ext_vector_type(8))) __bf16 bf16x8;
typedef __attribute__((ext_vector_type(4))) float f32x4;

__device__ __forceinline__ float bf2f(unsigned int h) { return __uint_as_float(h << 16); }
__device__ __forceinline__ u16 f2bf(float f) {
    unsigned int u = __float_as_uint(f);
    u += 0x7FFFu + ((u >> 16) & 1u);   // RNE
    return (u16)(u >> 16);
}
__device__ __forceinline__ void load8(const u16* p, float* v) {
    uint4 u = *(const uint4*)p;
    v[0] = bf2f(u.x & 0xffffu); v[1] = bf2f(u.x >> 16);
    v[2] = bf2f(u.y & 0xffffu); v[3] = bf2f(u.y >> 16);
    v[4] = bf2f(u.z & 0xffffu); v[5] = bf2f(u.z >> 16);
    v[6] = bf2f(u.w & 0xffffu); v[7] = bf2f(u.w >> 16);
}
__device__ __forceinline__ uint4 pack8(const float* v) {
    uint4 u;
    u.x = (unsigned)f2bf(v[0]) | ((unsigned)f2bf(v[1]) << 16);
    u.y = (unsigned)f2bf(v[2]) | ((unsigned)f2bf(v[3]) << 16);
    u.z = (unsigned)f2bf(v[4]) | ((unsigned)f2bf(v[5]) << 16);
    u.w = (unsigned)f2bf(v[6]) | ((unsigned)f2bf(v[7]) << 16);
    return u;
}
__device__ __forceinline__ void async16(const u16* g, u16* lds) {
    __builtin_amdgcn_global_load_lds(
        (const __attribute__((address_space(1))) unsigned int*)g,
        (__attribute__((address_space(3))) unsigned int*)lds, 16, 0, 0);
}

// ==== prep: foldq | wconv(concat_w) | wconv(mix_w2) | wmix1 | ctxbf ======
__global__ void prep_kernel(const float* __restrict__ in_proj_w,
                            const float* __restrict__ in_proj_b,
                            const float* __restrict__ qb,
                            const float* __restrict__ concat_w,
                            const float* __restrict__ mix_w1,
                            const float* __restrict__ mix_w2,
                            const float* __restrict__ context,
                            float* __restrict__ bqp,
                            u16* __restrict__ cwbf, u16* __restrict__ m1bf,
                            u16* __restrict__ m2bf, u16* __restrict__ ctxbf) {
    const int bid = blockIdx.x;
    const int tid = threadIdx.x;
    if (bid < 128) {
        const int wave = tid >> 6, lane = tid & 63;
        const int j = bid * 4 + wave;
        const int i = lane * 8;
        float4 w0 = *(const float4*)(in_proj_w + (size_t)j * 512 + i);
        float4 w1 = *(const float4*)(in_proj_w + (size_t)j * 512 + i + 4);
        float4 b0 = *(const float4*)(qb + i);
        float4 b1 = *(const float4*)(qb + i + 4);
        float p1 = w0.x*b0.x + w0.y*b0.y + w0.z*b0.z + w0.w*b0.w
                 + w1.x*b1.x + w1.y*b1.y + w1.z*b1.z + w1.w*b1.w;
        for (int m = 1; m < 64; m <<= 1) p1 += __shfl_xor(p1, m, 64);
        if (lane == 0) bqp[j] = in_proj_b[j] + p1;
    } else if (bid < 320) {
        int i = (bid - 128) * 256 + tid;           // < 49152
        const float* s = concat_w + (size_t)i * 8;
        float4 a = *(const float4*)s;
        float4 b = *(const float4*)(s + 4);
        float v[8] = {a.x, a.y, a.z, a.w, b.x, b.y, b.z, b.w};
        *(uint4*)(cwbf + (size_t)i * 8) = pack8(v);
    } else if (bid < 576) {
        int i = (bid - 320) * 256 + tid;           // < 65536
        const float* s = mix_w2 + (size_t)i * 8;
        float4 a = *(const float4*)s;
        float4 b = *(const float4*)(s + 4);
        float v[8] = {a.x, a.y, a.z, a.w, b.x, b.y, b.z, b.w};
        *(uint4*)(m2bf + (size_t)i * 8) = pack8(v);
    } else if (bid < 1344) {
        int idx = (bid - 576) * 256 + tid;         // < 196608
        int n = idx / 192;
        int k = (idx - n * 192) * 8;
        const float* base = mix_w1 + (size_t)n * 2048;
        float v[8];
        if (k < 512) {
            #pragma unroll
            for (int e = 0; e < 8; e++) v[e] = base[k + e] + base[1024 + k + e];
        } else if (k < 1024) {
            #pragma unroll
            for (int e = 0; e < 8; e++) v[e] = base[k + e] - base[512 + k + e];
        } else {
            #pragma unroll
            for (int e = 0; e < 8; e++) v[e] = base[512 + k + e];
        }
        *(uint4*)(m1bf + (size_t)n * 1536 + k) = pack8(v);
    } else {
        for (int i = tid; i < 2048; i += 256)
            ctxbf[i] = f2bf(context[i]);
    }
}

// ==== context stage A ====================================================
__global__ void ctx_stage_a(const float* __restrict__ context,
                            const float* __restrict__ film_w, const float* __restrict__ film_b,
                            const float* __restrict__ gate_w, const float* __restrict__ gate_b,
                            const float* __restrict__ ctx_w1, const float* __restrict__ ctx_b1,
                            float* __restrict__ gb1, float* __restrict__ betab,
                            float* __restrict__ gateb, float* __restrict__ hbuf) {
    const int wave = threadIdx.x >> 6, lane = threadIdx.x & 63;
    const int widx = blockIdx.x * 4 + wave;       // 0..16383
    const int b   = widx >> 11;
    const int j2  = widx & 2047;
    const int cat = j2 >> 9;
    const int j   = j2 & 511;
    const float* wrow;
    if      (cat == 0) wrow = film_w + (size_t)j * 256;
    else if (cat == 1) wrow = film_w + (size_t)(512 + j) * 256;
    else if (cat == 2) wrow = gate_w + (size_t)j * 256;
    else               wrow = ctx_w1 + (size_t)j * 256;
    float4 wv = *(const float4*)(wrow + lane * 4);
    float4 cv = *(const float4*)(context + b * 256 + lane * 4);
    float s = wv.x * cv.x + wv.y * cv.y + wv.z * cv.z + wv.w * cv.w;
    for (int m = 1; m < 64; m <<= 1) s += __shfl_xor(s, m, 64);
    if (lane == 0) {
        if      (cat == 0) gb1[b * 512 + j]   = 1.0f + s + film_b[j];
        else if (cat == 1) betab[b * 512 + j] = s + film_b[512 + j];
        else if (cat == 2) gateb[b * 512 + j] = 1.f / (1.f + expf(-(s + gate_b[j])));
        else {
            float hv = s + ctx_b1[j];
            hbuf[b * 512 + j] = 0.5f * hv * (1.0f + erff(hv * 0.70710678118654752f));
        }
    }
}

// ==== context stage B ====================================================
__global__ void ctx_stage_b(const float* __restrict__ hbuf,
                            const float* __restrict__ ctx_w2, const float* __restrict__ ctx_b2,
                            float* __restrict__ tokbuf) {
    const int wave = threadIdx.x >> 6, lane = threadIdx.x & 63;
    const int widx = blockIdx.x * 4 + wave;       // 0..8191
    const int b = widx >> 10;
    const int j = widx & 1023;
    const float* wrow = ctx_w2 + (size_t)j * 512 + lane * 8;
    const float* hr   = hbuf + b * 512 + lane * 8;
    float4 w0 = *(const float4*)wrow, w1 = *(const float4*)(wrow + 4);
    float4 h0 = *(const float4*)hr,   h1 = *(const float4*)(hr + 4);
    float s = w0.x*h0.x + w0.y*h0.y + w0.z*h0.z + w0.w*h0.w
            + w1.x*h1.x + w1.y*h1.y + w1.z*h1.z + w1.w*h1.w;
    for (int m = 1; m < 64; m <<= 1) s += __shfl_xor(s, m, 64);
    if (lane == 0) tokbuf[b * 1024 + j] = s + ctx_b2[j];
}

// ==== context stage C ====================================================
__global__ void ctx_stage_c(const float* __restrict__ tokbuf,
                            const float* __restrict__ in_proj_w, const float* __restrict__ in_proj_b,
                            float* __restrict__ kbuf, float* __restrict__ vbuf) {
    const int wave = threadIdx.x >> 6, lane = threadIdx.x & 63;
    const int widx = blockIdx.x * 4 + wave;       // 0..16383
    const int b  = widx >> 11;
    const int r  = widx & 2047;
    const int t  = r >> 10;
    const int kv = (r >> 9) & 1;
    const int j  = r & 511;
    const float* wrow = in_proj_w + (size_t)(512 + kv * 512 + j) * 512 + lane * 8;
    const float* tk   = tokbuf + (b * 2 + t) * 512 + lane * 8;
    float4 w0 = *(const float4*)wrow, w1 = *(const float4*)(wrow + 4);
    float4 t0 = *(const float4*)tk,   t1 = *(const float4*)(tk + 4);
    float s = w0.x*t0.x + w0.y*t0.y + w0.z*t0.z + w0.w*t0.w
            + w1.x*t1.x + w1.y*t1.y + w1.z*t1.z + w1.w*t1.w;
    for (int m = 1; m < 64; m <<= 1) s += __shfl_xor(s, m, 64);
    if (lane == 0) {
        float v = s + in_proj_b[512 + kv * 512 + j];
        if (kv == 0) kbuf[(b * 2 + t) * 512 + j] = v;
        else         vbuf[(b * 2 + t) * 512 + j] = v;
    }
}

// ==== context stage D: u/su/c0 (bid<32) and vo (bid>=32) =================
__global__ void ctx_stage_d(const float* __restrict__ in_proj_w,
                            const float* __restrict__ out_proj_w,
                            const float* __restrict__ qg, const float* __restrict__ bqp,
                            const float* __restrict__ kbuf, const float* __restrict__ vbuf,
                            float* __restrict__ ubuf, float* __restrict__ vobuf,
                            float* __restrict__ subuf, float* __restrict__ c0buf) {
    const int tid = threadIdx.x;
    __shared__ float sh[256];
    __shared__ float red[256];
    if (blockIdx.x < 32) {
        const int bid = blockIdx.x;
        const int b = bid >> 2, idx = bid & 3;
        const int t = idx >> 1, h = idx & 1;
        sh[tid] = kbuf[(b * 2 + t) * 512 + h * 256 + tid];
        __syncthreads();
        float a0 = 0.f, a1 = 0.f;
        #pragma unroll 4
        for (int dd = 0; dd < 256; dd++) {
            const float kv = sh[dd];
            const float* wr = in_proj_w + (size_t)(h * 256 + dd) * 512;
            a0 += kv * wr[tid];
            a1 += kv * wr[tid + 256];
        }
        float u0 = a0 * qg[tid], u1 = a1 * qg[tid + 256];
        ubuf[bid * 512 + tid]       = u0;
        ubuf[bid * 512 + tid + 256] = u1;
        red[tid] = u0 + u1;
        __syncthreads();
        for (int s = 128; s > 0; s >>= 1) { if (tid < s) red[tid] += red[tid + s]; __syncthreads(); }
        if (tid == 0) subuf[bid] = red[0];
        __syncthreads();
        red[tid] = bqp[h * 256 + tid] * sh[tid];
        __syncthreads();
        for (int s = 128; s > 0; s >>= 1) { if (tid < s) red[tid] += red[tid + s]; __syncthreads(); }
        if (tid == 0) c0buf[bid] = red[0];
    } else {
        const int bid = blockIdx.x - 32;
        const int b = bid >> 2, idx = bid & 3;
        const int t = idx >> 1, h = idx & 1;
        sh[tid] = vbuf[(b * 2 + t) * 512 + h * 256 + tid];
        __syncthreads();
        const float* w0 = out_proj_w + (size_t)tid * 512 + h * 256;
        const float* w1 = out_proj_w + (size_t)(tid + 256) * 512 + h * 256;
        float acc0 = 0.f, acc1 = 0.f;
        #pragma unroll 2
        for (int dd = 0; dd < 256; dd += 4) {
            float4 x0 = *(const float4*)(w0 + dd);
            float4 x1 = *(const float4*)(w1 + dd);
            acc0 += x0.x*sh[dd] + x0.y*sh[dd+1] + x0.z*sh[dd+2] + x0.w*sh[dd+3];
            acc1 += x1.x*sh[dd] + x1.y*sh[dd+1] + x1.z*sh[dd+2] + x1.w*sh[dd+3];
        }
        vobuf[bid * 512 + tid]       = acc0;
        vobuf[bid * 512 + tid + 256] = acc1;
    }
}

// ==== fused stats + attn, 2 rows per wave, half-range ====================
// writes xbf->mixA[:,0:512], ao->mixA[:,512:1024], x*ao->pbufH (local rows)
__global__ void statsattn_kernel(const float* __restrict__ x, float* __restrict__ stats,
                                 u16* __restrict__ mixA, u16* __restrict__ pbufH,
                                 const float* __restrict__ ubuf, const float* __restrict__ subuf,
                                 const float* __restrict__ c0buf, const float* __restrict__ vobuf,
                                 const float* __restrict__ ob, const int rowbase) {
    const int wave = threadIdx.x >> 6, lane = threadIdx.x & 63;
    const size_t lr = (size_t)blockIdx.x * 8 + wave * 2;   // local rows lr, lr+1
    const size_t gr = lr + rowbase;
    const int b = (int)(gr >> 12);                          // same for both rows
    float v[2][8], s[2] = {0.f, 0.f}, ss[2] = {0.f, 0.f};
    #pragma unroll
    for (int r = 0; r < 2; r++) {
        const float* xr = x + (gr + r) * 512 + lane * 8;
        float4 a = *(const float4*)xr;
        float4 c = *(const float4*)(xr + 4);
        v[r][0]=a.x; v[r][1]=a.y; v[r][2]=a.z; v[r][3]=a.w;
        v[r][4]=c.x; v[r][5]=c.y; v[r][6]=c.z; v[r][7]=c.w;
        #pragma unroll
        for (int e = 0; e < 8; e++) { s[r] += v[r][e]; ss[r] += v[r][e] * v[r][e]; }
    }
    float u[4][8];
    #pragma unroll
    for (int idx = 0; idx < 4; idx++) {
        const float* up = ubuf + (b * 4 + idx) * 512 + lane * 8;
        float4 u0 = *(const float4*)up, u1 = *(const float4*)(up + 4);
        u[idx][0]=u0.x; u[idx][1]=u0.y; u[idx][2]=u0.z; u[idx][3]=u0.w;
        u[idx][4]=u1.x; u[idx][5]=u1.y; u[idx][6]=u1.z; u[idx][7]=u1.w;
    }
    float sd[2][4];
    #pragma unroll
    for (int r = 0; r < 2; r++)
        #pragma unroll
        for (int idx = 0; idx < 4; idx++) {
            float acc = 0.f;
            #pragma unroll
            for (int e = 0; e < 8; e++) acc += v[r][e] * u[idx][e];
            sd[r][idx] = acc;
        }
    for (int m = 1; m < 64; m <<= 1) {
        #pragma unroll
        for (int r = 0; r < 2; r++) {
            s[r] += __shfl_xor(s[r], m, 64); ss[r] += __shfl_xor(ss[r], m, 64);
            #pragma unroll
            for (int idx = 0; idx < 4; idx++) sd[r][idx] += __shfl_xor(sd[r][idx], m, 64);
        }
    }
    float vo[4][8];
    #pragma unroll
    for (int idx = 0; idx < 4; idx++) {
        const float* vp = vobuf + (b * 4 + idx) * 512 + lane * 8;
        float4 v0 = *(const float4*)vp, v1 = *(const float4*)(vp + 4);
        vo[idx][0]=v0.x; vo[idx][1]=v0.y; vo[idx][2]=v0.z; vo[idx][3]=v0.w;
        vo[idx][4]=v1.x; vo[idx][5]=v1.y; vo[idx][6]=v1.z; vo[idx][7]=v1.w;
    }
    float obp[8];
    {
        const float* op = ob + lane * 8;
        float4 o0 = *(const float4*)op, o1 = *(const float4*)(op + 4);
        obp[0]=o0.x; obp[1]=o0.y; obp[2]=o0.z; obp[3]=o0.w;
        obp[4]=o1.x; obp[5]=o1.y; obp[6]=o1.z; obp[7]=o1.w;
    }
    #pragma unroll
    for (int r = 0; r < 2; r++) {
        const float mean = s[r] * (1.f / 512.f);
        const float rstd = rsqrtf(ss[r] * (1.f / 512.f) - mean * mean + 1e-5f);
        if (lane == 0) { stats[(gr + r) * 2] = mean; stats[(gr + r) * 2 + 1] = rstd; }
        float sc[4];
        #pragma unroll
        for (int idx = 0; idx < 4; idx++)
            sc[idx] = (rstd * (sd[r][idx] - mean * subuf[b * 4 + idx]) + c0buf[b * 4 + idx]) * (1.f / 16.f);
        float p[4];
        #pragma unroll
        for (int h = 0; h < 2; h++) {
            float s0 = sc[h], s1 = sc[2 + h];
            float mx = fmaxf(s0, s1);
            float e0 = expf(s0 - mx), e1 = expf(s1 - mx);
            float inv = 1.f / (e0 + e1);
            p[h] = e0 * inv; p[2 + h] = e1 * inv;
        }
        float o[8], pr[8];
        #pragma unroll
        for (int e = 0; e < 8; e++) {
            o[e] = p[0]*vo[0][e] + p[1]*vo[1][e] + p[2]*vo[2][e] + p[3]*vo[3][e] + obp[e];
            pr[e] = v[r][e] * o[e];
        }
        *(uint4*)(mixA + (gr + r) * 1024 + lane * 8)       = pack8(v[r]);
        *(uint4*)(mixA + (gr + r) * 1024 + 512 + lane * 8) = pack8(o);
        *(uint4*)(pbufH + (lr + r) * 512 + lane * 8)       = pack8(pr);
    }
}

// ==== MFMA GEMM, XOR-swizzled LDS, vectorized LDS-transpose epilogue =====
// AMODE 0: A = A0 (bf16, leading dim lda)
// AMODE 1: A = [A0(xbf, ld 1024) | A1(ctxbf, per-batch broadcast)], K=768
// AMODE 2: A = [A0(mixA, ld 1024, k<1024) | A1(pbufH, ld 512)], K=1536, all async
template<int AMODE, bool RELU>
__launch_bounds__(256)
__global__ void mfma_gemm(const u16* __restrict__ A0, const u16* __restrict__ A1,
                          const u16* __restrict__ Wb, const float* __restrict__ bias,
                          u16* __restrict__ out, const int K, const int lda, const int ldo) {
    __shared__ __align__(16) u16 S[16384];
    u16* As = S;
    u16* Bs = S + 8192;
    const int tid = threadIdx.x;
    const int w = tid >> 6, l = tid & 63;
    const int wm = w >> 1, wn = w & 1;
    const size_t m0 = (size_t)blockIdx.x * 128;
    const int n0 = blockIdx.y * 128;
    const int rb = w * 8 + (l >> 3);              // staging row base 0..31
    const int kswz = ((l & 7) ^ (l >> 3)) * 8;    // XOR-swizzled k offset
    const int bidx = (int)(m0 >> 12);
    const int quad = l >> 4, lc = l & 15;

    f32x4 acc[4][4];
    #pragma unroll
    for (int i = 0; i < 4; i++)
        #pragma unroll
        for (int j = 0; j < 4; j++) acc[i][j] = (f32x4){0.f, 0.f, 0.f, 0.f};

    for (int k0 = 0; k0 < K; k0 += 64) {
        __syncthreads();
        if constexpr (AMODE == 0) {
            #pragma unroll
            for (int r = 0; r < 4; r++)
                async16(A0 + (m0 + r * 32 + rb) * (size_t)lda + k0 + kswz, &As[r * 2048 + w * 512]);
        } else if constexpr (AMODE == 1) {
            if (k0 < 512) {
                #pragma unroll
                for (int r = 0; r < 4; r++)
                    async16(A0 + (m0 + r * 32 + rb) * (size_t)lda + k0 + kswz, &As[r * 2048 + w * 512]);
            } else {
                #pragma unroll
                for (int r = 0; r < 4; r++)
                    async16(A1 + bidx * 256 + (k0 - 512) + kswz, &As[r * 2048 + w * 512]);
            }
        } else {
            if (k0 < 1024) {       // [x | ao] in mixA (ld 1024)
                #pragma unroll
                for (int r = 0; r < 4; r++)
                    async16(A0 + (m0 + r * 32 + rb) * (size_t)1024 + k0 + kswz, &As[r * 2048 + w * 512]);
            } else {               // x*ao in pbufH (ld 512, local rows)
                #pragma unroll
                for (int r = 0; r < 4; r++)
                    async16(A1 + (m0 + r * 32 + rb) * (size_t)512 + (k0 - 1024) + kswz, &As[r * 2048 + w * 512]);
            }
        }
        #pragma unroll
        for (int r = 0; r < 4; r++)
            async16(Wb + (size_t)(n0 + r * 32 + rb) * K + k0 + kswz, &Bs[r * 2048 + w * 512]);
        __syncthreads();
        #pragma unroll
        for (int kk = 0; kk < 2; kk++) {
            bf16x8 af[4], bff[4];
            #pragma unroll
            for (int t = 0; t < 4; t++) {
                const int ch = ((kk << 2) | quad) ^ (lc & 7);
                af[t]  = *(const bf16x8*)&As[(wm * 64 + t * 16 + lc) * 64 + ch * 8];
                bff[t] = *(const bf16x8*)&Bs[(wn * 64 + t * 16 + lc) * 64 + ch * 8];
            }
            #pragma unroll
            for (int i = 0; i < 4; i++)
                #pragma unroll
                for (int j = 0; j < 4; j++)
                    acc[i][j] = __builtin_amdgcn_mfma_f32_16x16x32_bf16(af[i], bff[j], acc[i][j], 0, 0, 0);
        }
    }

    float bv[4];
    #pragma unroll
    for (int j = 0; j < 4; j++) bv[j] = bias[n0 + wn * 64 + j * 16 + lc];
    const int erow = tid >> 2;           // 0..63
    const int ecb  = (tid & 3) * 32;
    __syncthreads();
    #pragma unroll
    for (int p = 0; p < 2; p++) {
        if (p) __syncthreads();
        if (wm == p) {
            #pragma unroll
            for (int i = 0; i < 4; i++)
                #pragma unroll
                for (int j = 0; j < 4; j++)
                    #pragma unroll
                    for (int reg = 0; reg < 4; reg++) {
                        float vv = acc[i][j][reg] + bv[j];
                        if (RELU) vv = fmaxf(vv, 0.f);
                        S[(i * 16 + quad * 4 + reg) * 136 + wn * 64 + j * 16 + lc] = f2bf(vv);
                    }
        }
        __syncthreads();
        #pragma unroll
        for (int q = 0; q < 4; q++)
            *(uint4*)(out + (m0 + p * 64 + erow) * (size_t)ldo + n0 + ecb + q * 8)
                = *(const uint4*)&S[erow * 136 + ecb + q * 8];
    }
}

// ==== final: upd_c = LN(bufc); LN(base + gate*mask*(upd_c+upd_a)) ========
__global__ void final_kernel(const u16* __restrict__ mixA, const float* __restrict__ stats,
                             const u16* __restrict__ bufc,
                             const float* __restrict__ cg, const float* __restrict__ cb,
                             const float* __restrict__ gb1, const float* __restrict__ betab,
                             const float* __restrict__ gateb, const int* __restrict__ mask,
                             const float* __restrict__ fg, const float* __restrict__ fb,
                             const float* __restrict__ og, const float* __restrict__ ob,
                             float* __restrict__ out) {
    const int wave = threadIdx.x >> 6, lane = threadIdx.x & 63;
    const size_t row = (size_t)blockIdx.x * 4 + wave;
    const int b = (int)(row >> 12);
    const int c0 = lane * 8;
    float xv[8], uc[8], ua[8];
    load8(mixA + row * 1024 + c0, xv);          // xbf
    load8(mixA + row * 1024 + 512 + c0, ua);    // upd_a
    load8(bufc + row * 512 + c0, uc);           // relu'd concat out (pre-LN)
    float sc = 0.f, ssc = 0.f;
    #pragma unroll
    for (int e = 0; e < 8; e++) { sc += uc[e]; ssc += uc[e] * uc[e]; }
    for (int m = 1; m < 64; m <<= 1) { sc += __shfl_xor(sc, m, 64); ssc += __shfl_xor(ssc, m, 64); }
    const float mc = sc * (1.f / 512.f);
    const float rc = rsqrtf(ssc * (1.f / 512.f) - mc * mc + 1e-5f);
    const float mean = stats[row * 2], rstd = stats[row * 2 + 1];
    const float mf = (mask[row] != 0) ? 1.f : 0.f;
    float y[8];
    float s = 0.f, ss = 0.f;
    #pragma unroll
    for (int e = 0; e < 8; e++) {
        int c = c0 + e;
        float ucn = (uc[e] - mc) * rc * cg[c] + cb[c];
        float xh = (xv[e] - mean) * rstd;
        float base = gb1[b * 512 + c] * (xh * fg[c] + fb[c]) + betab[b * 512 + c];
        float yv = base + gateb[b * 512 + c] * mf * (ucn + ua[e]);
        y[e] = yv; s += yv; ss += yv * yv;
    }
    for (int m = 1; m < 64; m <<= 1) { s += __shfl_xor(s, m, 64); ss += __shfl_xor(ss, m, 64); }
    float mean2 = s * (1.f / 512.f);
    float rstd2 = rsqrtf(ss * (1.f / 512.f) - mean2 * mean2 + 1e-5f);
    float o[8];
    #pragma unroll
    for (int e = 0; e < 8; e++) {
        int c = c0 + e;
        o[e] = (y[e] - mean2) * rstd2 * og[c] + ob[c];
    }
    *(float4*)(out + row * 512 + c0)     = make_float4(o[0], o[1], o[2], o[3]);
    *(float4*)(out + row * 512 + c0 + 4) = make_float4(o[4], o[5], o[6], o[7]);
}

extern "C" void kernel_launch(void* const* d_in, const int* in_sizes, int n_in,
                              void* d_out, int out_size, void* d_ws, size_t ws_size,
                              hipStream_t stream) {
    const float* x          = (const float*)d_in[0];
    const float* context    = (const float*)d_in[1];
    const int*   mask       = (const int*)d_in[2];
    const float* film_ln_g  = (const float*)d_in[3];
    const float* film_ln_b  = (const float*)d_in[4];
    const float* film_w     = (const float*)d_in[5];
    const float* film_b     = (const float*)d_in[6];
    const float* concat_w   = (const float*)d_in[7];
    const float* concat_b   = (const float*)d_in[8];
    const float* concat_ln_g= (const float*)d_in[9];
    const float* concat_ln_b= (const float*)d_in[10];
    const float* ctx_w1     = (const float*)d_in[11];
    const float* ctx_b1     = (const float*)d_in[12];
    const float* ctx_w2     = (const float*)d_in[13];
    const float* ctx_b2     = (const float*)d_in[14];
    const float* q_ln_g     = (const float*)d_in[15];
    const float* q_ln_b     = (const float*)d_in[16];
    const float* in_proj_w  = (const float*)d_in[17];
    const float* in_proj_b  = (const float*)d_in[18];
    const float* out_proj_w = (const float*)d_in[19];
    const float* out_proj_b = (const float*)d_in[20];
    const float* mix_w1     = (const float*)d_in[21];
    const float* mix_b1     = (const float*)d_in[22];
    const float* mix_w2     = (const float*)d_in[23];
    const float* mix_b2     = (const float*)d_in[24];
    const float* out_ln_g   = (const float*)d_in[25];
    const float* out_ln_b   = (const float*)d_in[26];
    const float* gate_w     = (const float*)d_in[27];
    const float* gate_b     = (const float*)d_in[28];
    float* out = (float*)d_out;

    // ---- workspace layout (~156.6 MB) ----
    float* gb1    = (float*)d_ws;            // 4096
    float* betab  = gb1 + 4096;
    float* gateb  = betab + 4096;
    float* kbuf   = gateb + 4096;            // 8192
    float* vbuf   = kbuf + 8192;
    float* bqp    = vbuf + 8192;             // 512
    float* hbuf   = bqp + 512;               // 4096
    float* tokbuf = hbuf + 4096;             // 8192
    float* ubuf   = tokbuf + 8192;           // 16384
    float* vobuf  = ubuf + 16384;            // 16384
    float* subuf  = vobuf + 16384;           // 32
    float* c0buf  = subuf + 32;              // 32
    float* stats  = c0buf + 32;              // 65536
    u16* ctxbf = (u16*)(stats + 65536);      // 2048
    u16* cwbf  = ctxbf + 2048;               // 393216
    u16* m1bf  = cwbf + 393216;              // 1572864
    u16* m2bf  = m1bf + 1572864;             // 524288
    u16* mixA  = m2bf + 524288;                        // 32768*1024 [xbf | ao->upd_a]
    u16* bufc  = mixA + (size_t)N_TOK * 1024;          // 32768*512  relu concat out
    u16* pbufH = bufc + (size_t)N_TOK * 512;           // 16384*512  x*ao (per half)
    u16* bufhH = pbufH + (size_t)HALF_ROWS * 512;      // 16384*1024 h (per half)

    prep_kernel<<<1345, 256, 0, stream>>>(in_proj_w, in_proj_b, q_ln_b,
                                          concat_w, mix_w1, mix_w2, context,
                                          bqp, cwbf, m1bf, m2bf, ctxbf);
    ctx_stage_a<<<4096, 256, 0, stream>>>(context, film_w, film_b, gate_w, gate_b,
                                          ctx_w1, ctx_b1, gb1, betab, gateb, hbuf);
    ctx_stage_b<<<2048, 256, 0, stream>>>(hbuf, ctx_w2, ctx_b2, tokbuf);
    ctx_stage_c<<<4096, 256, 0, stream>>>(tokbuf, in_proj_w, in_proj_b, kbuf, vbuf);
    ctx_stage_d<<<64, 256, 0, stream>>>(in_proj_w, out_proj_w, q_ln_g, bqp,
                                        kbuf, vbuf, ubuf, vobuf, subuf, c0buf);

    // mix pipeline, two halves; pbufH/bufhH reused per half
    for (int h = 0; h < 2; h++) {
        const int rowbase = h * HALF_ROWS;
        statsattn_kernel<<<HALF_ROWS / 8, 256, 0, stream>>>(
            x, stats, mixA, pbufH, ubuf, subuf, c0buf, vobuf, out_proj_b, rowbase);
        mfma_gemm<2, true><<<dim3(128, 8), 256, 0, stream>>>(
            mixA + (size_t)rowbase * 1024, pbufH, m1bf, mix_b1,
            bufhH, 1536, 1024, 1024);
        mfma_gemm<0, false><<<dim3(128, 4), 256, 0, stream>>>(
            bufhH, nullptr, m2bf, mix_b2,
            mixA + (size_t)rowbase * 1024 + 512, 1024, 1024, 1024);
    }

    // concat: relu([x|ctx] @ concat_w^T + b) -> bufc (LN folded into final)
    mfma_gemm<1, true><<<dim3(256, 4), 256, 0, stream>>>(
        mixA, ctxbf, cwbf, concat_b, bufc, 768, 1024, 512);

    final_kernel<<<N_TOK / 4, 256, 0, stream>>>(mixA, stats, bufc,
                                                concat_ln_g, concat_ln_b,
                                                gb1, betab, gateb, mask,
                                                film_ln_g, film_ln_b,
                                                out_ln_g, out_ln_b, out);
    (void)in_sizes; (void)n_in; (void)out_size; (void)ws_size;
}